// Round 15
// baseline (104.394 us; speedup 1.0000x reference)
//
#include <hip/hip_runtime.h>
#include <hip/hip_bf16.h>

#define BB 16
#define NN 64
#define AA 8400
#define CC 20
#define TOPKK 13
#define NG 33         // anchor groups of 256 (33*256 = 8448 >= AA)
#define SEGCAP 48     // max positives (al>0) per (row, group)
#define ROWCAP 128    // max positives per row

__device__ __forceinline__ int inside_pt(float gx1, float gy1, float gx2, float gy2,
                                         float ax, float ay) {
    float d = fminf(fminf(ax - gx1, ay - gy1), fminf(gx2 - ax, gy2 - ay));
    return d > 1e-9f;
}

__device__ __forceinline__ float atan_wh4(float4 b) {
    return atanf((b.z - b.x) / ((b.w - b.y) + 1e-7f));
}

__device__ __forceinline__ float ciou_clip(float4 g, float4 p, float at_p, float at_g) {
    const float eps = 1e-7f;
    float w1 = g.z - g.x, h1 = g.w - g.y;
    float w2 = p.z - p.x, h2 = p.w - p.y;
    float ix = fmaxf(fminf(g.z, p.z) - fmaxf(g.x, p.x), 0.0f);
    float iy = fmaxf(fminf(g.w, p.w) - fmaxf(g.y, p.y), 0.0f);
    float inter = ix * iy;
    float uni = w1 * h1 + w2 * h2 - inter + eps;
    float iou = inter / uni;
    float cw = fmaxf(g.z, p.z) - fminf(g.x, p.x);
    float ch = fmaxf(g.w, p.w) - fminf(g.y, p.y);
    float c2 = cw * cw + ch * ch + eps;
    float dx = p.x + p.z - g.x - g.z;
    float dy = p.y + p.w - g.y - g.w;
    float rho2 = (dx * dx + dy * dy) * 0.25f;
    float at = at_p - at_g;
    float v = 0.40528473456935109f * (at * at);
    float alpha = v / (v - iou + 1.0000001f);
    return fmaxf(iou - (rho2 / c2 + v * alpha), 0.0f);
}

// max-ov, tie -> smallest n (matches jnp.argmax first-max over masked overlaps)
__device__ __forceinline__ unsigned long long pack_ov(float ov, int n) {
    return ((unsigned long long)__float_as_uint(ov) << 6) | (unsigned)(63 - n);
}
__device__ __forceinline__ int unpack_n(unsigned long long k) {
    return 63 - (int)(k & 63ull);
}

// K1: thread-per-anchor scan (inside-mask + dense CIoU), winner, segment lists.
// Also zeroes pos_bits, out_scores, done. Grid: BB*NG = 528 blocks x 256.
__global__ __launch_bounds__(256) void k1_scan(
    const float* __restrict__ pd_scores, const float4* __restrict__ pd_bboxes,
    const float2* __restrict__ anc, const int* __restrict__ gt_labels, int lab_stride,
    const float4* __restrict__ gt_bboxes, const float* __restrict__ mask_gt,
    unsigned long long* __restrict__ pos_bits, unsigned long long* __restrict__ winner,
    int* __restrict__ cnt,
    float* __restrict__ g_val, float* __restrict__ g_ov, int* __restrict__ g_ai,
    float4* __restrict__ out_scores4, int* __restrict__ done)
{
    __shared__ float4 lds_gt[NN];
    __shared__ float  lds_atg[NN];
    __shared__ int    lds_lab[NN];
    __shared__ int    lds_cnt[NN];

    const int tid  = threadIdx.x;
    const int gtid = blockIdx.x * 256 + tid;
    const int lane = tid & 63;
    const int NTH  = BB * NG * 256;

    if (gtid < BB * AA) pos_bits[gtid] = 0ull;   // consumed by K2's atomicOr
    if (gtid < BB) done[gtid] = 0;               // K2 last-block counters
    float4 z4 = make_float4(0.f, 0.f, 0.f, 0.f);
    for (int i = gtid; i < BB * AA * 5; i += NTH) out_scores4[i] = z4;

    const int b    = blockIdx.x / NG;
    const int grp  = blockIdx.x - b * NG;
    const int rowb = b * NN;

    if (tid < NN) {
        float4 g4 = gt_bboxes[rowb + tid];
        lds_gt[tid]  = g4;
        lds_atg[tid] = atan_wh4(g4);
        int lab = gt_labels[(rowb + tid) * lab_stride];
        lds_lab[tid] = (mask_gt[rowb + tid] > 0.0f) ? lab : -1;
        lds_cnt[tid] = 0;
    }
    __syncthreads();

    unsigned long long vmask = __ballot(lds_lab[lane] >= 0);   // wave-uniform

    int a = grp * 256 + tid;
    bool va = a < AA;
    float2 ap = va ? anc[a] : make_float2(-1e9f, -1e9f);
    float4 p  = va ? pd_bboxes[(size_t)b * AA + a] : make_float4(0.f, 0.f, 0.f, 1.f);
    float atp = atan_wh4(p);
    const float* psb = pd_scores + ((size_t)b * AA + a) * CC;

    // Phase A: inside mask
    unsigned long long im = 0ull;
    if (va) {
        unsigned long long m = vmask;
        while (m) {
            int n = __ffsll((unsigned long long)m) - 1;
            m &= m - 1;
            float4 g4 = lds_gt[n];
            if (inside_pt(g4.x, g4.y, g4.z, g4.w, ap.x, ap.y)) im |= 1ull << n;
        }
    }

    // Phase B: dense CIoU over own inside gts
    unsigned long long wmax = pack_ov(0.0f, 0);   // all-zero row argmax -> n=0
    unsigned long long m = im;
    while (m) {
        int n = __ffsll((unsigned long long)m) - 1;
        m &= m - 1;
        float4 g4 = lds_gt[n];
        float ov = ciou_clip(g4, p, atp, lds_atg[n]);
        unsigned long long key = pack_ov(ov, n);
        if (key > wmax) wmax = key;
        float o2 = ov * ov;
        float al = psb[lds_lab[n]] * (o2 * o2 * o2);
        if (al > 0.0f) {
            int slot = atomicAdd(&lds_cnt[n], 1);
            if (slot < SEGCAP) {
                size_t o = ((size_t)(rowb + n) * NG + grp) * SEGCAP + slot;
                g_val[o] = al; g_ov[o] = ov; g_ai[o] = a;
            }
        }
    }
    if (va) winner[(size_t)b * AA + a] = wmax;     // sole writer: plain store

    __syncthreads();
    if (tid < NN) cnt[(size_t)(rowb + tid) * NG + grp] = min(lds_cnt[tid], SEGCAP);
}

// K2: per-row top-13 (one wave per row, 4 rows/block; 16 blocks per batch),
// then the LAST block of each batch (done-counter) runs the output phase for
// the whole batch. 2 dispatches total, no grid sync, no spinning.
__global__ __launch_bounds__(256) void k2_fused(
    const float* __restrict__ pd_scores, const float4* __restrict__ pd_bboxes,
    const float2* __restrict__ anc, const int* __restrict__ gt_labels, int lab_stride,
    const float4* __restrict__ gt_bboxes, const float* __restrict__ mask_gt,
    const int* __restrict__ cnt,
    const float* __restrict__ g_val, const float* __restrict__ g_ov,
    const int* __restrict__ g_ai,
    unsigned long long* __restrict__ pos_bits,
    const unsigned long long* __restrict__ winner,
    int* __restrict__ cand_idx, float* __restrict__ cand_ov,
    float* __restrict__ cand_al, int* __restrict__ cand_cnt,
    int* __restrict__ done,
    float* __restrict__ out_labels, float* __restrict__ out_bboxes,
    float* __restrict__ out_scores, float* __restrict__ out_fg,
    float* __restrict__ out_tgt)
{
    __shared__ unsigned short smap[4][ROWCAP];
    __shared__ int s_last;
    const int tid  = threadIdx.x;
    const int lane = tid & 63;
    const int wid  = tid >> 6;
    const int r    = blockIdx.x * 4 + wid;   // row 0..1023
    const int b = r >> 6, n = r & 63;
    const int batch = blockIdx.x >> 4;       // 16 blocks per batch

    float mg = mask_gt[r];
    bool active = mg > 0.0f;

    int c = 0;
    if (active && lane < NG) c = cnt[(size_t)r * NG + lane];
    int incl = c;
    #pragma unroll
    for (int off = 1; off < 64; off <<= 1) {
        int y = __shfl_up(incl, off);
        if (lane >= off) incl += y;
    }
    int excl = incl - c;
    int p_all = __shfl(incl, 63);

    if (active) {
        for (int k = 0; k < c; ++k) {
            int q = excl + k;
            if (q < ROWCAP) smap[wid][q] = (unsigned short)((lane << 6) | k);
        }
    }
    __syncthreads();   // block-uniform

    int p = min(p_all, ROWCAP);
    float v0 = -1.0f, v1 = -1.0f, ovr0 = 0.0f, ovr1 = 0.0f;
    int a0 = 1 << 30, a1 = 1 << 30;
    if (active) {
        if (lane < p) {
            int m = smap[wid][lane]; int w = m >> 6, k = m & 63;
            size_t o = ((size_t)r * NG + w) * SEGCAP + k;
            v0 = g_val[o]; ovr0 = g_ov[o]; a0 = g_ai[o];
        }
        if (lane + 64 < p) {
            int m = smap[wid][lane + 64]; int w = m >> 6, k = m & 63;
            size_t o = ((size_t)r * NG + w) * SEGCAP + k;
            v1 = g_val[o]; ovr1 = g_ov[o]; a1 = g_ai[o];
        }
    }
    int nr = active ? min(p, TOPKK) : 0;
    for (int k = 0; k < nr; ++k) {
        float bv; int ba; float bo;
        if (v0 > v1 || (v0 == v1 && a0 < a1)) { bv = v0; ba = a0; bo = ovr0; }
        else                                   { bv = v1; ba = a1; bo = ovr1; }
        #pragma unroll
        for (int s2 = 32; s2 > 0; s2 >>= 1) {
            float v2 = __shfl_xor(bv, s2);
            int   aa2 = __shfl_xor(ba, s2);
            float o2 = __shfl_xor(bo, s2);
            if (v2 > bv || (v2 == bv && aa2 < ba)) { bv = v2; ba = aa2; bo = o2; }
        }
        if (lane == 0) {
            cand_idx[r * TOPKK + k] = ba;
            cand_ov[r * TOPKK + k]  = bo;
            cand_al[r * TOPKK + k]  = bv;
            atomicOr(&pos_bits[(size_t)b * AA + ba], 1ull << n);
        }
        if (a0 == ba) v0 = -1.0f;
        if (a1 == ba) v1 = -1.0f;
    }

    int nsel_final;
    if (active && p < TOPKK) {
        // zeros admitted at smallest anchor indices (all within a<32); emit inside ones
        int st = 1; float so = 0.0f;
        if (lane < 32) {
            float4 g4 = gt_bboxes[r];
            float2 apx = anc[lane];
            int ins = inside_pt(g4.x, g4.y, g4.z, g4.w, apx.x, apx.y);
            float o = 0.0f, al = 0.0f;
            if (ins) {
                float4 pp = pd_bboxes[(size_t)b * AA + lane];
                o = ciou_clip(g4, pp, atan_wh4(pp), atan_wh4(g4));
                int label = gt_labels[r * lab_stride];
                float sc = pd_scores[((size_t)b * AA + lane) * CC + label];
                float o2 = o * o;
                al = sc * (o2 * o2 * o2);
            }
            so = o;
            st = (al == 0.0f) ? (ins ? 2 : 1) : 0;
        }
        int nsel = nr, need = TOPKK - p;
        for (int a2 = 0; a2 < 32; ++a2) {
            int sta = __shfl(st, a2);
            float oa = __shfl(so, a2);
            if (lane == 0 && need > 0 && sta != 0) {
                if (sta == 2) {
                    cand_idx[r * TOPKK + nsel] = a2;
                    cand_ov[r * TOPKK + nsel]  = oa;
                    cand_al[r * TOPKK + nsel]  = 0.0f;
                    atomicOr(&pos_bits[(size_t)b * AA + a2], 1ull << n);
                    nsel++;
                }
                need--;
            }
        }
        nsel_final = nsel;
    } else {
        nsel_final = active ? nr : 0;
    }
    if (lane == 0) {
        cand_cnt[r] = nsel_final;
        for (int j = nsel_final; j < TOPKK; ++j) {
            cand_idx[r * TOPKK + j] = 0;
            cand_ov[r * TOPKK + j]  = 0.0f;
            cand_al[r * TOPKK + j]  = 0.0f;
        }
    }

    // ---- last-block-per-batch output phase ---------------------------------
    __syncthreads();                 // all 4 rows of this block published
    if (tid == 0) {
        __threadfence();             // release: our stores + atomics visible
        int old = atomicAdd(&done[batch], 1);
        s_last = (old == 15);
    }
    __syncthreads();
    if (!s_last) return;
    __threadfence();                 // acquire: see all 16 blocks' stores

    for (int a = tid; a < AA; a += 256) {
        size_t i = (size_t)batch * AA + a;
        unsigned long long bits = pos_bits[i];
        unsigned long long wi   = winner[i];
        if (__popcll(bits) > 1) bits &= (1ull << unpack_n(wi));

        int fg = bits != 0ull;
        int tgt = fg ? (__ffsll((unsigned long long)bits) - 1) : 0;
        int row = batch * NN + tgt;
        int label = gt_labels[row * lab_stride];
        label = label > 0 ? label : 0;
        float4 g = gt_bboxes[row];
        out_labels[i] = (float)label;
        ((float4*)out_bboxes)[i] = g;

        if (fg) {
            int cntn = cand_cnt[row];
            float al = 0.0f, pa = 0.0f, po = 0.0f;
            #pragma unroll
            for (int j = 0; j < TOPKK; ++j) {
                int aj   = cand_idx[row * TOPKK + j];   // sentinel 0 when j >= cntn
                float cal = cand_al[row * TOPKK + j];
                float cov = cand_ov[row * TOPKK + j];
                size_t oj = (size_t)batch * AA + aj;
                unsigned long long bj = pos_bits[oj];
                unsigned long long wj = winner[oj];
                bool valid = j < cntn;
                if (__popcll(bj) > 1) bj &= (1ull << unpack_n(wj));
                if (valid && ((bj >> tgt) & 1ull)) {
                    pa = fmaxf(pa, cal);
                    po = fmaxf(po, cov);
                }
                if (valid && aj == a) al = cal;
            }
            float norm = (al * po) / (pa + 1e-9f);
            out_scores[i * CC + label] = norm;
        }
        out_fg[i] = fg ? 1.0f : 0.0f;
        out_tgt[i] = (float)tgt;
    }
}

extern "C" void kernel_launch(void* const* d_in, const int* in_sizes, int n_in,
                              void* d_out, int out_size, void* d_ws, size_t ws_size,
                              hipStream_t stream) {
    const float*  pd_scores = (const float*)d_in[0];
    const float4* pd_bboxes = (const float4*)d_in[1];
    const float2* anc       = (const float2*)d_in[2];
    const int*    gt_labels = (const int*)d_in[3];
    const float4* gt_bboxes = (const float4*)d_in[4];
    const float*  mask_gt   = (const float*)d_in[5];
    int lab_stride = (in_sizes[3] == 2 * BB * NN) ? 2 : 1;  // int64 fallback

    const int BA = BB * AA;     // 134400
    const int BN = BB * NN;     // 1024

    char* ws = (char*)d_ws;
    size_t off = 0;
    unsigned long long* pos_bits = (unsigned long long*)(ws + off); off += (size_t)BA * 8;
    unsigned long long* winner   = (unsigned long long*)(ws + off); off += (size_t)BA * 8;
    int*   cnt      = (int*)(ws + off);    off += (size_t)BN * NG * 4;
    float* g_val    = (float*)(ws + off);  off += (size_t)BN * NG * SEGCAP * 4;
    float* g_ov     = (float*)(ws + off);  off += (size_t)BN * NG * SEGCAP * 4;
    int*   g_ai     = (int*)(ws + off);    off += (size_t)BN * NG * SEGCAP * 4;
    int*   cand_idx = (int*)(ws + off);    off += (size_t)BN * TOPKK * 4;
    float* cand_ov  = (float*)(ws + off);  off += (size_t)BN * TOPKK * 4;
    float* cand_al  = (float*)(ws + off);  off += (size_t)BN * TOPKK * 4;
    int*   cand_cnt = (int*)(ws + off);    off += (size_t)BN * 4;
    int*   done     = (int*)(ws + off);

    float* out_labels = (float*)d_out;
    float* out_bboxes = out_labels + BA;
    float* out_scores = out_bboxes + (size_t)BA * 4;
    float* out_fg     = out_scores + (size_t)BA * CC;
    float* out_tgt    = out_fg + BA;

    k1_scan<<<BB * NG, 256, 0, stream>>>(
        pd_scores, pd_bboxes, anc, gt_labels, lab_stride, gt_bboxes, mask_gt,
        pos_bits, winner, cnt, g_val, g_ov, g_ai, (float4*)out_scores, done);
    k2_fused<<<BN / 4, 256, 0, stream>>>(
        pd_scores, pd_bboxes, anc, gt_labels, lab_stride, gt_bboxes, mask_gt,
        cnt, g_val, g_ov, g_ai, pos_bits, winner,
        cand_idx, cand_ov, cand_al, cand_cnt, done,
        out_labels, out_bboxes, out_scores, out_fg, out_tgt);
}

// Round 16
// 73.780 us; speedup vs baseline: 1.4149x; 1.4149x over previous
//
#include <hip/hip_runtime.h>
#include <hip/hip_bf16.h>

#define BB 16
#define NN 64
#define AA 8400
#define CC 20
#define TOPKK 13
#define NG 33         // anchor groups of 256 (33*256 = 8448 >= AA)
#define SEGCAP 48     // max positives (al>0) per (row, group)
#define ROWCAP 128    // max positives per row
#define SLICE 525     // AA / 16 slices per batch (525*16 = 8400)

__device__ __forceinline__ int inside_pt(float gx1, float gy1, float gx2, float gy2,
                                         float ax, float ay) {
    float d = fminf(fminf(ax - gx1, ay - gy1), fminf(gx2 - ax, gy2 - ay));
    return d > 1e-9f;
}

__device__ __forceinline__ float atan_wh4(float4 b) {
    return atanf((b.z - b.x) / ((b.w - b.y) + 1e-7f));
}

__device__ __forceinline__ float ciou_clip(float4 g, float4 p, float at_p, float at_g) {
    const float eps = 1e-7f;
    float w1 = g.z - g.x, h1 = g.w - g.y;
    float w2 = p.z - p.x, h2 = p.w - p.y;
    float ix = fmaxf(fminf(g.z, p.z) - fmaxf(g.x, p.x), 0.0f);
    float iy = fmaxf(fminf(g.w, p.w) - fmaxf(g.y, p.y), 0.0f);
    float inter = ix * iy;
    float uni = w1 * h1 + w2 * h2 - inter + eps;
    float iou = inter / uni;
    float cw = fmaxf(g.z, p.z) - fminf(g.x, p.x);
    float ch = fmaxf(g.w, p.w) - fminf(g.y, p.y);
    float c2 = cw * cw + ch * ch + eps;
    float dx = p.x + p.z - g.x - g.z;
    float dy = p.y + p.w - g.y - g.w;
    float rho2 = (dx * dx + dy * dy) * 0.25f;
    float at = at_p - at_g;
    float v = 0.40528473456935109f * (at * at);
    float alpha = v / (v - iou + 1.0000001f);
    return fmaxf(iou - (rho2 / c2 + v * alpha), 0.0f);
}

// max-ov, tie -> smallest n (matches jnp.argmax first-max over masked overlaps)
__device__ __forceinline__ unsigned long long pack_ov(float ov, int n) {
    return ((unsigned long long)__float_as_uint(ov) << 6) | (unsigned)(63 - n);
}
__device__ __forceinline__ int unpack_n(unsigned long long k) {
    return 63 - (int)(k & 63ull);
}

// K1: thread-per-anchor scan (inside-mask + dense CIoU), winner, segment lists.
// Also zeroes pos_bits, out_scores, done. Grid: BB*NG = 528 blocks x 256.
__global__ __launch_bounds__(256) void k1_scan(
    const float* __restrict__ pd_scores, const float4* __restrict__ pd_bboxes,
    const float2* __restrict__ anc, const int* __restrict__ gt_labels, int lab_stride,
    const float4* __restrict__ gt_bboxes, const float* __restrict__ mask_gt,
    unsigned long long* __restrict__ pos_bits, unsigned long long* __restrict__ winner,
    int* __restrict__ cnt,
    float* __restrict__ g_val, float* __restrict__ g_ov, int* __restrict__ g_ai,
    float4* __restrict__ out_scores4, int* __restrict__ done)
{
    __shared__ float4 lds_gt[NN];
    __shared__ float  lds_atg[NN];
    __shared__ int    lds_lab[NN];
    __shared__ int    lds_cnt[NN];

    const int tid  = threadIdx.x;
    const int gtid = blockIdx.x * 256 + tid;
    const int lane = tid & 63;
    const int NTH  = BB * NG * 256;

    if (gtid < BB * AA) pos_bits[gtid] = 0ull;   // consumed by K2's atomicOr
    if (gtid < BB) done[gtid] = 0;               // K2 per-batch arrival counters
    float4 z4 = make_float4(0.f, 0.f, 0.f, 0.f);
    for (int i = gtid; i < BB * AA * 5; i += NTH) out_scores4[i] = z4;

    const int b    = blockIdx.x / NG;
    const int grp  = blockIdx.x - b * NG;
    const int rowb = b * NN;

    if (tid < NN) {
        float4 g4 = gt_bboxes[rowb + tid];
        lds_gt[tid]  = g4;
        lds_atg[tid] = atan_wh4(g4);
        int lab = gt_labels[(rowb + tid) * lab_stride];
        lds_lab[tid] = (mask_gt[rowb + tid] > 0.0f) ? lab : -1;
        lds_cnt[tid] = 0;
    }
    __syncthreads();

    unsigned long long vmask = __ballot(lds_lab[lane] >= 0);   // wave-uniform

    int a = grp * 256 + tid;
    bool va = a < AA;
    float2 ap = va ? anc[a] : make_float2(-1e9f, -1e9f);
    float4 p  = va ? pd_bboxes[(size_t)b * AA + a] : make_float4(0.f, 0.f, 0.f, 1.f);
    float atp = atan_wh4(p);
    const float* psb = pd_scores + ((size_t)b * AA + a) * CC;

    // Phase A: inside mask
    unsigned long long im = 0ull;
    if (va) {
        unsigned long long m = vmask;
        while (m) {
            int n = __ffsll((unsigned long long)m) - 1;
            m &= m - 1;
            float4 g4 = lds_gt[n];
            if (inside_pt(g4.x, g4.y, g4.z, g4.w, ap.x, ap.y)) im |= 1ull << n;
        }
    }

    // Phase B: dense CIoU over own inside gts
    unsigned long long wmax = pack_ov(0.0f, 0);   // all-zero row argmax -> n=0
    unsigned long long m = im;
    while (m) {
        int n = __ffsll((unsigned long long)m) - 1;
        m &= m - 1;
        float4 g4 = lds_gt[n];
        float ov = ciou_clip(g4, p, atp, lds_atg[n]);
        unsigned long long key = pack_ov(ov, n);
        if (key > wmax) wmax = key;
        float o2 = ov * ov;
        float al = psb[lds_lab[n]] * (o2 * o2 * o2);
        if (al > 0.0f) {
            int slot = atomicAdd(&lds_cnt[n], 1);
            if (slot < SEGCAP) {
                size_t o = ((size_t)(rowb + n) * NG + grp) * SEGCAP + slot;
                g_val[o] = al; g_ov[o] = ov; g_ai[o] = a;
            }
        }
    }
    if (va) winner[(size_t)b * AA + a] = wmax;     // sole writer: plain store

    __syncthreads();
    if (tid < NN) cnt[(size_t)(rowb + tid) * NG + grp] = min(lds_cnt[tid], SEGCAP);
}

// K2: topk (4 waves x 1 row per block; 16 blocks per batch) -> per-batch
// arrival counter -> bounded spin (all 256 blocks co-resident at 1/CU) ->
// WIDE output: each block outputs a 525-anchor slice of its batch.
__global__ __launch_bounds__(256, 2) void k2_fused(
    const float* __restrict__ pd_scores, const float4* __restrict__ pd_bboxes,
    const float2* __restrict__ anc, const int* __restrict__ gt_labels, int lab_stride,
    const float4* __restrict__ gt_bboxes, const float* __restrict__ mask_gt,
    const int* __restrict__ cnt,
    const float* __restrict__ g_val, const float* __restrict__ g_ov,
    const int* __restrict__ g_ai,
    unsigned long long* __restrict__ pos_bits,
    const unsigned long long* __restrict__ winner,
    int* __restrict__ cand_idx, float* __restrict__ cand_ov,
    float* __restrict__ cand_al, int* __restrict__ cand_cnt,
    int* __restrict__ done,
    float* __restrict__ out_labels, float* __restrict__ out_bboxes,
    float* __restrict__ out_scores, float* __restrict__ out_fg,
    float* __restrict__ out_tgt)
{
    __shared__ unsigned short smap[4][ROWCAP];
    const int tid  = threadIdx.x;
    const int lane = tid & 63;
    const int wid  = tid >> 6;
    const int r    = blockIdx.x * 4 + wid;   // row 0..1023
    const int b = r >> 6, n = r & 63;
    const int batch = blockIdx.x >> 4;       // 16 blocks per batch
    const int slice = blockIdx.x & 15;

    float mg = mask_gt[r];
    bool active = mg > 0.0f;

    int c = 0;
    if (active && lane < NG) c = cnt[(size_t)r * NG + lane];
    int incl = c;
    #pragma unroll
    for (int off = 1; off < 64; off <<= 1) {
        int y = __shfl_up(incl, off);
        if (lane >= off) incl += y;
    }
    int excl = incl - c;
    int p_all = __shfl(incl, 63);

    if (active) {
        for (int k = 0; k < c; ++k) {
            int q = excl + k;
            if (q < ROWCAP) smap[wid][q] = (unsigned short)((lane << 6) | k);
        }
    }
    __syncthreads();   // block-uniform

    int p = min(p_all, ROWCAP);
    float v0 = -1.0f, v1 = -1.0f, ovr0 = 0.0f, ovr1 = 0.0f;
    int a0 = 1 << 30, a1 = 1 << 30;
    if (active) {
        if (lane < p) {
            int m = smap[wid][lane]; int w = m >> 6, k = m & 63;
            size_t o = ((size_t)r * NG + w) * SEGCAP + k;
            v0 = g_val[o]; ovr0 = g_ov[o]; a0 = g_ai[o];
        }
        if (lane + 64 < p) {
            int m = smap[wid][lane + 64]; int w = m >> 6, k = m & 63;
            size_t o = ((size_t)r * NG + w) * SEGCAP + k;
            v1 = g_val[o]; ovr1 = g_ov[o]; a1 = g_ai[o];
        }
    }
    int nr = active ? min(p, TOPKK) : 0;
    for (int k = 0; k < nr; ++k) {
        float bv; int ba; float bo;
        if (v0 > v1 || (v0 == v1 && a0 < a1)) { bv = v0; ba = a0; bo = ovr0; }
        else                                   { bv = v1; ba = a1; bo = ovr1; }
        #pragma unroll
        for (int s2 = 32; s2 > 0; s2 >>= 1) {
            float v2 = __shfl_xor(bv, s2);
            int   aa2 = __shfl_xor(ba, s2);
            float o2 = __shfl_xor(bo, s2);
            if (v2 > bv || (v2 == bv && aa2 < ba)) { bv = v2; ba = aa2; bo = o2; }
        }
        if (lane == 0) {
            cand_idx[r * TOPKK + k] = ba;
            cand_ov[r * TOPKK + k]  = bo;
            cand_al[r * TOPKK + k]  = bv;
            atomicOr(&pos_bits[(size_t)b * AA + ba], 1ull << n);
        }
        if (a0 == ba) v0 = -1.0f;
        if (a1 == ba) v1 = -1.0f;
    }

    int nsel_final;
    if (active && p < TOPKK) {
        // zeros admitted at smallest anchor indices (all within a<32); emit inside ones
        int st = 1; float so = 0.0f;
        if (lane < 32) {
            float4 g4 = gt_bboxes[r];
            float2 apx = anc[lane];
            int ins = inside_pt(g4.x, g4.y, g4.z, g4.w, apx.x, apx.y);
            float o = 0.0f, al = 0.0f;
            if (ins) {
                float4 pp = pd_bboxes[(size_t)b * AA + lane];
                o = ciou_clip(g4, pp, atan_wh4(pp), atan_wh4(g4));
                int label = gt_labels[r * lab_stride];
                float sc = pd_scores[((size_t)b * AA + lane) * CC + label];
                float o2 = o * o;
                al = sc * (o2 * o2 * o2);
            }
            so = o;
            st = (al == 0.0f) ? (ins ? 2 : 1) : 0;
        }
        int nsel = nr, need = TOPKK - p;
        for (int a2 = 0; a2 < 32; ++a2) {
            int sta = __shfl(st, a2);
            float oa = __shfl(so, a2);
            if (lane == 0 && need > 0 && sta != 0) {
                if (sta == 2) {
                    cand_idx[r * TOPKK + nsel] = a2;
                    cand_ov[r * TOPKK + nsel]  = oa;
                    cand_al[r * TOPKK + nsel]  = 0.0f;
                    atomicOr(&pos_bits[(size_t)b * AA + a2], 1ull << n);
                    nsel++;
                }
                need--;
            }
        }
        nsel_final = nsel;
    } else {
        nsel_final = active ? nr : 0;
    }
    if (lane == 0) {
        cand_cnt[r] = nsel_final;
        for (int j = nsel_final; j < TOPKK; ++j) {
            cand_idx[r * TOPKK + j] = 0;
            cand_ov[r * TOPKK + j]  = 0.0f;
            cand_al[r * TOPKK + j]  = 0.0f;
        }
    }

    // ---- per-batch arrival + bounded spin (all blocks co-resident) ----------
    __syncthreads();                 // this block's 4 rows published
    if (tid == 0) {
        __threadfence();             // release
        __hip_atomic_fetch_add(&done[batch], 1, __ATOMIC_ACQ_REL, __HIP_MEMORY_SCOPE_AGENT);
        while (__hip_atomic_load(&done[batch], __ATOMIC_ACQUIRE, __HIP_MEMORY_SCOPE_AGENT) < 16)
            __builtin_amdgcn_s_sleep(8);
    }
    __syncthreads();
    __threadfence();                 // acquire: see all 16 sibling blocks' stores

    // ---- WIDE output: this block's 525-anchor slice of its batch ------------
    for (int a = slice * SLICE + tid; a < (slice + 1) * SLICE; a += 256) {
        size_t i = (size_t)batch * AA + a;
        unsigned long long bits = pos_bits[i];
        unsigned long long wi   = winner[i];
        if (__popcll(bits) > 1) bits &= (1ull << unpack_n(wi));

        int fg = bits != 0ull;
        int tgt = fg ? (__ffsll((unsigned long long)bits) - 1) : 0;
        int row = batch * NN + tgt;
        int label = gt_labels[row * lab_stride];
        label = label > 0 ? label : 0;
        float4 g = gt_bboxes[row];
        out_labels[i] = (float)label;
        ((float4*)out_bboxes)[i] = g;

        if (fg) {
            int cntn = cand_cnt[row];
            float al = 0.0f, pa = 0.0f, po = 0.0f;
            #pragma unroll
            for (int j = 0; j < TOPKK; ++j) {
                int aj   = cand_idx[row * TOPKK + j];   // sentinel 0 when j >= cntn
                float cal = cand_al[row * TOPKK + j];
                float cov = cand_ov[row * TOPKK + j];
                size_t oj = (size_t)batch * AA + aj;
                unsigned long long bj = pos_bits[oj];
                unsigned long long wj = winner[oj];
                bool valid = j < cntn;
                if (__popcll(bj) > 1) bj &= (1ull << unpack_n(wj));
                if (valid && ((bj >> tgt) & 1ull)) {
                    pa = fmaxf(pa, cal);
                    po = fmaxf(po, cov);
                }
                if (valid && aj == a) al = cal;
            }
            float norm = (al * po) / (pa + 1e-9f);
            out_scores[i * CC + label] = norm;
        }
        out_fg[i] = fg ? 1.0f : 0.0f;
        out_tgt[i] = (float)tgt;
    }
}

extern "C" void kernel_launch(void* const* d_in, const int* in_sizes, int n_in,
                              void* d_out, int out_size, void* d_ws, size_t ws_size,
                              hipStream_t stream) {
    const float*  pd_scores = (const float*)d_in[0];
    const float4* pd_bboxes = (const float4*)d_in[1];
    const float2* anc       = (const float2*)d_in[2];
    const int*    gt_labels = (const int*)d_in[3];
    const float4* gt_bboxes = (const float4*)d_in[4];
    const float*  mask_gt   = (const float*)d_in[5];
    int lab_stride = (in_sizes[3] == 2 * BB * NN) ? 2 : 1;  // int64 fallback

    const int BA = BB * AA;     // 134400
    const int BN = BB * NN;     // 1024

    char* ws = (char*)d_ws;
    size_t off = 0;
    unsigned long long* pos_bits = (unsigned long long*)(ws + off); off += (size_t)BA * 8;
    unsigned long long* winner   = (unsigned long long*)(ws + off); off += (size_t)BA * 8;
    int*   cnt      = (int*)(ws + off);    off += (size_t)BN * NG * 4;
    float* g_val    = (float*)(ws + off);  off += (size_t)BN * NG * SEGCAP * 4;
    float* g_ov     = (float*)(ws + off);  off += (size_t)BN * NG * SEGCAP * 4;
    int*   g_ai     = (int*)(ws + off);    off += (size_t)BN * NG * SEGCAP * 4;
    int*   cand_idx = (int*)(ws + off);    off += (size_t)BN * TOPKK * 4;
    float* cand_ov  = (float*)(ws + off);  off += (size_t)BN * TOPKK * 4;
    float* cand_al  = (float*)(ws + off);  off += (size_t)BN * TOPKK * 4;
    int*   cand_cnt = (int*)(ws + off);    off += (size_t)BN * 4;
    int*   done     = (int*)(ws + off);

    float* out_labels = (float*)d_out;
    float* out_bboxes = out_labels + BA;
    float* out_scores = out_bboxes + (size_t)BA * 4;
    float* out_fg     = out_scores + (size_t)BA * CC;
    float* out_tgt    = out_fg + BA;

    k1_scan<<<BB * NG, 256, 0, stream>>>(
        pd_scores, pd_bboxes, anc, gt_labels, lab_stride, gt_bboxes, mask_gt,
        pos_bits, winner, cnt, g_val, g_ov, g_ai, (float4*)out_scores, done);
    k2_fused<<<BN / 4, 256, 0, stream>>>(
        pd_scores, pd_bboxes, anc, gt_labels, lab_stride, gt_bboxes, mask_gt,
        cnt, g_val, g_ov, g_ai, pos_bits, winner,
        cand_idx, cand_ov, cand_al, cand_cnt, done,
        out_labels, out_bboxes, out_scores, out_fg, out_tgt);
}

// Round 17
// 36.583 us; speedup vs baseline: 2.8537x; 2.0168x over previous
//
#include <hip/hip_runtime.h>
#include <hip/hip_bf16.h>

#define BB 16
#define NN 64
#define AA 8400
#define CC 20
#define TOPKK 13
#define NG 33         // anchor groups of 256 (33*256 = 8448 >= AA)
#define SEGCAP 48     // max positives (al>0) per (row, group)
#define ROWCAP 128    // max positives per row

__device__ __forceinline__ int inside_pt(float gx1, float gy1, float gx2, float gy2,
                                         float ax, float ay) {
    float d = fminf(fminf(ax - gx1, ay - gy1), fminf(gx2 - ax, gy2 - ay));
    return d > 1e-9f;
}

__device__ __forceinline__ float atan_wh4(float4 b) {
    return atanf((b.z - b.x) / ((b.w - b.y) + 1e-7f));
}

__device__ __forceinline__ float ciou_clip(float4 g, float4 p, float at_p, float at_g) {
    const float eps = 1e-7f;
    float w1 = g.z - g.x, h1 = g.w - g.y;
    float w2 = p.z - p.x, h2 = p.w - p.y;
    float ix = fmaxf(fminf(g.z, p.z) - fmaxf(g.x, p.x), 0.0f);
    float iy = fmaxf(fminf(g.w, p.w) - fmaxf(g.y, p.y), 0.0f);
    float inter = ix * iy;
    float uni = w1 * h1 + w2 * h2 - inter + eps;
    float iou = inter / uni;
    float cw = fmaxf(g.z, p.z) - fminf(g.x, p.x);
    float ch = fmaxf(g.w, p.w) - fminf(g.y, p.y);
    float c2 = cw * cw + ch * ch + eps;
    float dx = p.x + p.z - g.x - g.z;
    float dy = p.y + p.w - g.y - g.w;
    float rho2 = (dx * dx + dy * dy) * 0.25f;
    float at = at_p - at_g;
    float v = 0.40528473456935109f * (at * at);
    float alpha = v / (v - iou + 1.0000001f);
    return fmaxf(iou - (rho2 / c2 + v * alpha), 0.0f);
}

// max-ov, tie -> smallest n (matches jnp.argmax first-max over masked overlaps)
__device__ __forceinline__ unsigned long long pack_ov(float ov, int n) {
    return ((unsigned long long)__float_as_uint(ov) << 6) | (unsigned)(63 - n);
}
__device__ __forceinline__ int unpack_n(unsigned long long k) {
    return 63 - (int)(k & 63ull);
}

// pw[i] = { .x = pos_bits, .y = winner } — one 16B line per anchor.

// K1: thread-per-anchor scan (inside-mask + dense CIoU), winner, segment lists.
// Zeroes pw[].x. Grid: BB*NG = 528 blocks x 256.
__global__ __launch_bounds__(256) void k1_scan(
    const float* __restrict__ pd_scores, const float4* __restrict__ pd_bboxes,
    const float2* __restrict__ anc, const int* __restrict__ gt_labels, int lab_stride,
    const float4* __restrict__ gt_bboxes, const float* __restrict__ mask_gt,
    ulonglong2* __restrict__ pw,
    int* __restrict__ cnt,
    float* __restrict__ g_val, float* __restrict__ g_ov, int* __restrict__ g_ai)
{
    __shared__ float4 lds_gt[NN];
    __shared__ float  lds_atg[NN];
    __shared__ int    lds_lab[NN];
    __shared__ int    lds_cnt[NN];

    const int tid  = threadIdx.x;
    const int gtid = blockIdx.x * 256 + tid;
    const int lane = tid & 63;

    if (gtid < BB * AA) pw[gtid].x = 0ull;   // pos_bits zero; .y written below

    const int b    = blockIdx.x / NG;
    const int grp  = blockIdx.x - b * NG;
    const int rowb = b * NN;

    if (tid < NN) {
        float4 g4 = gt_bboxes[rowb + tid];
        lds_gt[tid]  = g4;
        lds_atg[tid] = atan_wh4(g4);
        int lab = gt_labels[(rowb + tid) * lab_stride];
        lds_lab[tid] = (mask_gt[rowb + tid] > 0.0f) ? lab : -1;
        lds_cnt[tid] = 0;
    }
    __syncthreads();

    unsigned long long vmask = __ballot(lds_lab[lane] >= 0);   // wave-uniform

    int a = grp * 256 + tid;
    bool va = a < AA;
    float2 ap = va ? anc[a] : make_float2(-1e9f, -1e9f);
    float4 p  = va ? pd_bboxes[(size_t)b * AA + a] : make_float4(0.f, 0.f, 0.f, 1.f);
    float atp = atan_wh4(p);
    const float* psb = pd_scores + ((size_t)b * AA + a) * CC;

    // Phase A: inside mask
    unsigned long long im = 0ull;
    if (va) {
        unsigned long long m = vmask;
        while (m) {
            int n = __ffsll((unsigned long long)m) - 1;
            m &= m - 1;
            float4 g4 = lds_gt[n];
            if (inside_pt(g4.x, g4.y, g4.z, g4.w, ap.x, ap.y)) im |= 1ull << n;
        }
    }

    // Phase B: dense CIoU over own inside gts
    unsigned long long wmax = pack_ov(0.0f, 0);   // all-zero row argmax -> n=0
    unsigned long long m = im;
    while (m) {
        int n = __ffsll((unsigned long long)m) - 1;
        m &= m - 1;
        float4 g4 = lds_gt[n];
        float ov = ciou_clip(g4, p, atp, lds_atg[n]);
        unsigned long long key = pack_ov(ov, n);
        if (key > wmax) wmax = key;
        float o2 = ov * ov;
        float al = psb[lds_lab[n]] * (o2 * o2 * o2);
        if (al > 0.0f) {
            int slot = atomicAdd(&lds_cnt[n], 1);
            if (slot < SEGCAP) {
                size_t o = ((size_t)(rowb + n) * NG + grp) * SEGCAP + slot;
                g_val[o] = al; g_ov[o] = ov; g_ai[o] = a;
            }
        }
    }
    if (va) pw[(size_t)b * AA + a].y = wmax;       // sole writer: plain store

    __syncthreads();
    if (tid < NN) cnt[(size_t)(rowb + tid) * NG + grp] = min(lds_cnt[tid], SEGCAP);
}

// K2: per-row top-13 (one wave per row, 4 rows/block). Grid: 256 blocks x 256.
// Pads cand arrays to fixed TOPKK with sentinels so K3 can fully unroll.
__global__ __launch_bounds__(256) void k2_topk(
    const float* __restrict__ pd_scores, const float4* __restrict__ pd_bboxes,
    const float2* __restrict__ anc, const int* __restrict__ gt_labels, int lab_stride,
    const float4* __restrict__ gt_bboxes, const float* __restrict__ mask_gt,
    const int* __restrict__ cnt,
    const float* __restrict__ g_val, const float* __restrict__ g_ov,
    const int* __restrict__ g_ai,
    ulonglong2* __restrict__ pw,
    int* __restrict__ cand_idx, float* __restrict__ cand_ov,
    float* __restrict__ cand_al, int* __restrict__ cand_cnt)
{
    __shared__ unsigned short smap[4][ROWCAP];
    const int tid  = threadIdx.x;
    const int lane = tid & 63;
    const int wid  = tid >> 6;
    const int r    = blockIdx.x * 4 + wid;   // row 0..1023
    const int b = r >> 6, n = r & 63;

    float mg = mask_gt[r];
    bool active = mg > 0.0f;

    int c = 0;
    if (active && lane < NG) c = cnt[(size_t)r * NG + lane];
    int incl = c;
    #pragma unroll
    for (int off = 1; off < 64; off <<= 1) {
        int y = __shfl_up(incl, off);
        if (lane >= off) incl += y;
    }
    int excl = incl - c;
    int p_all = __shfl(incl, 63);

    if (active) {
        for (int k = 0; k < c; ++k) {
            int q = excl + k;
            if (q < ROWCAP) smap[wid][q] = (unsigned short)((lane << 6) | k);
        }
    }
    __syncthreads();   // block-uniform

    int p = min(p_all, ROWCAP);
    float v0 = -1.0f, v1 = -1.0f, ovr0 = 0.0f, ovr1 = 0.0f;
    int a0 = 1 << 30, a1 = 1 << 30;
    if (active) {
        if (lane < p) {
            int m = smap[wid][lane]; int w = m >> 6, k = m & 63;
            size_t o = ((size_t)r * NG + w) * SEGCAP + k;
            v0 = g_val[o]; ovr0 = g_ov[o]; a0 = g_ai[o];
        }
        if (lane + 64 < p) {
            int m = smap[wid][lane + 64]; int w = m >> 6, k = m & 63;
            size_t o = ((size_t)r * NG + w) * SEGCAP + k;
            v1 = g_val[o]; ovr1 = g_ov[o]; a1 = g_ai[o];
        }
    }
    int nr = active ? min(p, TOPKK) : 0;
    for (int k = 0; k < nr; ++k) {
        float bv; int ba; float bo;
        if (v0 > v1 || (v0 == v1 && a0 < a1)) { bv = v0; ba = a0; bo = ovr0; }
        else                                   { bv = v1; ba = a1; bo = ovr1; }
        #pragma unroll
        for (int s2 = 32; s2 > 0; s2 >>= 1) {
            float v2 = __shfl_xor(bv, s2);
            int   aa2 = __shfl_xor(ba, s2);
            float o2 = __shfl_xor(bo, s2);
            if (v2 > bv || (v2 == bv && aa2 < ba)) { bv = v2; ba = aa2; bo = o2; }
        }
        if (lane == 0) {
            cand_idx[r * TOPKK + k] = ba;
            cand_ov[r * TOPKK + k]  = bo;
            cand_al[r * TOPKK + k]  = bv;
            atomicOr(&pw[(size_t)b * AA + ba].x, 1ull << n);
        }
        if (a0 == ba) v0 = -1.0f;
        if (a1 == ba) v1 = -1.0f;
    }

    int nsel_final;
    if (active && p < TOPKK) {
        // zeros admitted at smallest anchor indices (all within a<32); emit inside ones
        int st = 1; float so = 0.0f;
        if (lane < 32) {
            float4 g4 = gt_bboxes[r];
            float2 apx = anc[lane];
            int ins = inside_pt(g4.x, g4.y, g4.z, g4.w, apx.x, apx.y);
            float o = 0.0f, al = 0.0f;
            if (ins) {
                float4 pp = pd_bboxes[(size_t)b * AA + lane];
                o = ciou_clip(g4, pp, atan_wh4(pp), atan_wh4(g4));
                int label = gt_labels[r * lab_stride];
                float sc = pd_scores[((size_t)b * AA + lane) * CC + label];
                float o2 = o * o;
                al = sc * (o2 * o2 * o2);
            }
            so = o;
            st = (al == 0.0f) ? (ins ? 2 : 1) : 0;
        }
        int nsel = nr, need = TOPKK - p;
        for (int a2 = 0; a2 < 32; ++a2) {
            int sta = __shfl(st, a2);
            float oa = __shfl(so, a2);
            if (lane == 0 && need > 0 && sta != 0) {
                if (sta == 2) {
                    cand_idx[r * TOPKK + nsel] = a2;
                    cand_ov[r * TOPKK + nsel]  = oa;
                    cand_al[r * TOPKK + nsel]  = 0.0f;
                    atomicOr(&pw[(size_t)b * AA + a2].x, 1ull << n);
                    nsel++;
                }
                need--;
            }
        }
        nsel_final = nsel;
    } else {
        nsel_final = active ? nr : 0;
    }
    if (lane == 0) {
        cand_cnt[r] = nsel_final;
        for (int j = nsel_final; j < TOPKK; ++j) {
            cand_idx[r * TOPKK + j] = 0;
            cand_ov[r * TOPKK + j]  = 0.0f;
            cand_al[r * TOPKK + j]  = 0.0f;
        }
    }
}

// K3: filter (packed pw loads) + outputs. Writes full score rows (5x float4,
// 16B-aligned since i*80 % 16 == 0) — single pass, no separate zero kernel.
__global__ __launch_bounds__(256) void k3_out(
    const ulonglong2* __restrict__ pw,
    const int* __restrict__ gt_labels, int lab_stride,
    const float4* __restrict__ gt_bboxes,
    const int* __restrict__ cand_idx, const float* __restrict__ cand_ov,
    const float* __restrict__ cand_al, const int* __restrict__ cand_cnt,
    float* __restrict__ out_labels, float* __restrict__ out_bboxes,
    float* __restrict__ out_scores, float* __restrict__ out_fg,
    float* __restrict__ out_tgt)
{
    int i = blockIdx.x * 256 + threadIdx.x;
    if (i >= BB * AA) return;
    int b = i / AA, a = i - b * AA;

    ulonglong2 v = pw[i];                       // one 16B coalesced load
    unsigned long long bits = v.x;
    if (__popcll(bits) > 1) bits &= (1ull << unpack_n(v.y));

    int fg = bits != 0ull;
    int tgt = fg ? (__ffsll((unsigned long long)bits) - 1) : 0;
    int row = b * NN + tgt;
    int label = gt_labels[row * lab_stride];
    label = label > 0 ? label : 0;
    float4 g = gt_bboxes[row];
    out_labels[i] = (float)label;
    ((float4*)out_bboxes)[i] = g;

    float norm = 0.0f;
    if (fg) {
        int cntn = cand_cnt[row];
        float al = 0.0f, pa = 0.0f, po = 0.0f;
        #pragma unroll
        for (int j = 0; j < TOPKK; ++j) {
            int aj   = cand_idx[row * TOPKK + j];   // sentinel 0 when j >= cntn
            float cal = cand_al[row * TOPKK + j];
            float cov = cand_ov[row * TOPKK + j];
            ulonglong2 vj = pw[(size_t)b * AA + aj]; // one scattered 16B load
            unsigned long long bj = vj.x;
            bool valid = j < cntn;
            if (__popcll(bj) > 1) bj &= (1ull << unpack_n(vj.y));
            if (valid && ((bj >> tgt) & 1ull)) {
                pa = fmaxf(pa, cal);
                po = fmaxf(po, cov);
            }
            if (valid && aj == a) al = cal;
        }
        norm = (al * po) / (pa + 1e-9f);
    }

    // full 20-float row, vectorized (16B aligned: i*80 bytes)
    float4* sc4 = (float4*)(out_scores + (size_t)i * CC);
    #pragma unroll
    for (int w = 0; w < 5; ++w) {
        float4 vv;
        vv.x = (4 * w + 0 == label && fg) ? norm : 0.0f;
        vv.y = (4 * w + 1 == label && fg) ? norm : 0.0f;
        vv.z = (4 * w + 2 == label && fg) ? norm : 0.0f;
        vv.w = (4 * w + 3 == label && fg) ? norm : 0.0f;
        sc4[w] = vv;
    }
    out_fg[i] = fg ? 1.0f : 0.0f;
    out_tgt[i] = (float)tgt;
}

extern "C" void kernel_launch(void* const* d_in, const int* in_sizes, int n_in,
                              void* d_out, int out_size, void* d_ws, size_t ws_size,
                              hipStream_t stream) {
    const float*  pd_scores = (const float*)d_in[0];
    const float4* pd_bboxes = (const float4*)d_in[1];
    const float2* anc       = (const float2*)d_in[2];
    const int*    gt_labels = (const int*)d_in[3];
    const float4* gt_bboxes = (const float4*)d_in[4];
    const float*  mask_gt   = (const float*)d_in[5];
    int lab_stride = (in_sizes[3] == 2 * BB * NN) ? 2 : 1;  // int64 fallback

    const int BA = BB * AA;     // 134400
    const int BN = BB * NN;     // 1024

    char* ws = (char*)d_ws;
    size_t off = 0;
    ulonglong2* pw = (ulonglong2*)(ws + off); off += (size_t)BA * 16;
    int*   cnt      = (int*)(ws + off);    off += (size_t)BN * NG * 4;
    float* g_val    = (float*)(ws + off);  off += (size_t)BN * NG * SEGCAP * 4;
    float* g_ov     = (float*)(ws + off);  off += (size_t)BN * NG * SEGCAP * 4;
    int*   g_ai     = (int*)(ws + off);    off += (size_t)BN * NG * SEGCAP * 4;
    int*   cand_idx = (int*)(ws + off);    off += (size_t)BN * TOPKK * 4;
    float* cand_ov  = (float*)(ws + off);  off += (size_t)BN * TOPKK * 4;
    float* cand_al  = (float*)(ws + off);  off += (size_t)BN * TOPKK * 4;
    int*   cand_cnt = (int*)(ws + off);

    float* out_labels = (float*)d_out;
    float* out_bboxes = out_labels + BA;
    float* out_scores = out_bboxes + (size_t)BA * 4;
    float* out_fg     = out_scores + (size_t)BA * CC;
    float* out_tgt    = out_fg + BA;

    k1_scan<<<BB * NG, 256, 0, stream>>>(
        pd_scores, pd_bboxes, anc, gt_labels, lab_stride, gt_bboxes, mask_gt,
        pw, cnt, g_val, g_ov, g_ai);
    k2_topk<<<BN / 4, 256, 0, stream>>>(
        pd_scores, pd_bboxes, anc, gt_labels, lab_stride, gt_bboxes, mask_gt,
        cnt, g_val, g_ov, g_ai, pw, cand_idx, cand_ov, cand_al, cand_cnt);
    k3_out<<<(BA + 255) / 256, 256, 0, stream>>>(
        pw, gt_labels, lab_stride, gt_bboxes,
        cand_idx, cand_ov, cand_al, cand_cnt,
        out_labels, out_bboxes, out_scores, out_fg, out_tgt);
}